// Round 19
// baseline (339.235 us; speedup 1.0000x reference)
//
#include <hip/hip_runtime.h>

#define N_NODES 50000
#define N_EDGES 600000
#define DIM     128
#define RR      4
#define LL      2
#define GG      512
#define CC      8
#define NCB     196                       // coarse buckets (nodes >> 8)
#define EC      (N_EDGES / 4)             // 150000
#define FB      ((EC + 255) / 256)        // 586 hist/sortA blocks
#define TB      ((N_NODES + 255) / 256)   // 196 tfill blocks
#define NBH     ((N_NODES + 63) / 64)     // 782 MFMA tile blocks
#define CB      (1026 + 3125)             // 4151 canon blocks

typedef short bf16x8 __attribute__((ext_vector_type(8)));
typedef float f32x4  __attribute__((ext_vector_type(4)));

// ---------- bf16 <-> f32 helpers ----------
__device__ __forceinline__ float bf16_to_f(unsigned short u) {
    return __uint_as_float(((unsigned int)u) << 16);
}
__device__ __forceinline__ unsigned short f_to_bf16(float f) {
    unsigned int u = __float_as_uint(f);
    u += 0x7FFFu + ((u >> 16) & 1u);   // RNE
    return (unsigned short)(u >> 16);
}
__device__ __forceinline__ float loadf(const void* p, long i, int isbf) {
    if (isbf) return bf16_to_f(((const unsigned short*)p)[i]);
    return ((const float*)p)[i];
}
__device__ __forceinline__ void storef(void* p, long i, float v, int isbf) {
    if (isbf) ((unsigned short*)p)[i] = f_to_bf16(v);
    else      ((float*)p)[i] = v;
}

// ---------- init: zero chist(196)+tb(16), dtype-detect. one block ----------
__global__ void cg_init(const unsigned int* __restrict__ xw, int* __restrict__ flag,
                        int* __restrict__ chist_tb) {
    __shared__ int cnt;
    int tid = threadIdx.x;
    if (tid < NCB + 16) chist_tb[tid] = 0;
    if (tid == 0) cnt = 0;
    __syncthreads();
    unsigned int w = xw[tid];
    unsigned int e = (w >> 7) & 0xFFu;
    atomicAdd(&cnt, (e >= 110u && e <= 133u) ? 1 : 0);
    __syncthreads();
    if (tid == 0) *flag = (cnt >= 128) ? 1 : 0;
}

// ---------- fused: coarse-bucket + node-type histograms [0,FB) + canonicalization ----------
__global__ void cg_hist_canon(const int* __restrict__ edge_index, const int* __restrict__ node_type,
                              int* __restrict__ chist, int* __restrict__ tb,
                              const void* __restrict__ x,
                              const void* __restrict__ W_het, const void* __restrict__ b_het,
                              const void* __restrict__ conv_W, const void* __restrict__ fuse_W,
                              const void* __restrict__ conv_b, const void* __restrict__ fuse_b,
                              const int* __restrict__ flagp,
                              unsigned short* __restrict__ xb, unsigned short* __restrict__ Wt,
                              float* __restrict__ bhf,
                              unsigned short* __restrict__ M2t, float* __restrict__ cvec) {
    __shared__ float s[256];
    int bk = blockIdx.x;
    int tid = threadIdx.x;
    if (bk < FB) {
        __shared__ int lh[NCB];
        __shared__ int loc[4];
        for (int i = tid; i < NCB; i += 256) lh[i] = 0;
        if (tid < 4) loc[tid] = 0;
        __syncthreads();
        int t = bk * 256 + tid;
        if (t < EC) {
#pragma unroll
            for (int k = 0; k < 4; k++) {
                int d = edge_index[N_EDGES + t + k * EC];
                atomicAdd(&lh[d >> 8], 1);
            }
        }
        if (t < N_NODES) atomicAdd(&loc[node_type[t]], 1);
        __syncthreads();
        for (int i = tid; i < NCB; i += 256)
            if (lh[i]) atomicAdd(&chist[i], lh[i]);
        if (tid < 4 && loc[tid]) atomicAdd(&tb[tid], loc[tid]);
        return;
    }
    int b = bk - FB;
    int isbf = *flagp;
    if (b < 512) {                      // M2t: 2 d-rows per block
        int lr = b >> 6;
        int d  = (b & 63) * 2 + (tid >> 7);
        int r  = lr & 3;
        int o  = tid & 127;
        float acc = 0.0f;
        for (int k = 0; k < DIM; k++) {
            acc += loadf(conv_W, (long)(lr * DIM + d) * DIM + k, isbf)
                 * loadf(fuse_W, (long)(r * DIM + k) * DIM + o, isbf);
        }
        M2t[((long)lr * DIM + o) * DIM + d] = f_to_bf16(acc);
    } else if (b < 768) {               // cvec
        int bc = b - 512;
        int l  = bc >> 7;
        int o  = bc & 127;
        float part = 0.0f;
        for (int rk = tid; rk < RR * DIM; rk += 256) {
            part += loadf(conv_b, (long)l * RR * DIM + rk, isbf)
                  * loadf(fuse_W, (long)rk * DIM + o, isbf);
        }
        s[tid] = part;
        __syncthreads();
        for (int off = 128; off > 0; off >>= 1) {
            if (tid < off) s[tid] += s[tid + off];
            __syncthreads();
        }
        if (tid == 0) cvec[bc] = s[0] + loadf(fuse_b, o, isbf);
    } else if (b < 1024) {              // Wt[t][o][d]; 2 (t,o) per block
        int pair = (b - 768) * 2 + (tid >> 7);
        int t = pair >> 7;
        int o = pair & 127;
        int d = tid & 127;
        float v = loadf(W_het, ((long)t * DIM + d) * DIM + o, isbf);
        Wt[((long)t * DIM + o) * DIM + d] = f_to_bf16(v);
    } else if (b < 1026) {              // bhf
        int idx = (b - 1024) * 256 + tid;
        if (idx < 4 * DIM) bhf[idx] = loadf(b_het, idx, isbf);
    } else {                            // xb: 8 elems/thread
        long i = ((long)(b - 1026) * 256 + tid) * 8;
        if (i >= (long)N_NODES * DIM) return;
        if (isbf) {
            *(uint4*)(xb + i) = *(const uint4*)((const unsigned short*)x + i);
        } else {
            const float* xf = (const float*)x + i;
            float4 f0 = *(const float4*)xf;
            float4 f1 = *(const float4*)(xf + 4);
            uint4 o;
            o.x = (unsigned int)f_to_bf16(f0.x) | ((unsigned int)f_to_bf16(f0.y) << 16);
            o.y = (unsigned int)f_to_bf16(f0.z) | ((unsigned int)f_to_bf16(f0.w) << 16);
            o.z = (unsigned int)f_to_bf16(f1.x) | ((unsigned int)f_to_bf16(f1.y) << 16);
            o.w = (unsigned int)f_to_bf16(f1.z) | ((unsigned int)f_to_bf16(f1.w) << 16);
            *(uint4*)(xb + i) = o;
        }
    }
}

// ---------- single-block: scan coarse hist -> blockoff/ccursor; scan tb ----------
__global__ void cg_scan196(const int* __restrict__ chist, int* __restrict__ blockoff,
                           int* __restrict__ ccursor, int* __restrict__ tb) {
    __shared__ int s[256];
    int tid = threadIdx.x;
    int v = (tid < NCB) ? chist[tid] : 0;
    s[tid] = v;
    __syncthreads();
    for (int off = 1; off < 256; off <<= 1) {
        int a = (tid >= off) ? s[tid - off] : 0;
        __syncthreads();
        s[tid] += a;
        __syncthreads();
    }
    if (tid < NCB) {
        int e = s[tid] - v;            // exclusive bucket start
        blockoff[tid] = e;
        ccursor[tid]  = e;
    }
    if (tid == 0) {
        int run = 0;
        for (int t = 0; t < 4; t++) {
            tb[8 + t] = run;
            tb[4 + t] = run;
            run += tb[t];
        }
        tb[12] = run;
    }
}

// ---------- node-type list fill (block-aggregated) ----------
__global__ void cg_tfill(const int* __restrict__ node_type, int* __restrict__ tb,
                         int* __restrict__ tlist) {
    __shared__ int lcur[4];
    __shared__ int lbase[4];
    int tid = threadIdx.x;
    if (tid < 4) lcur[tid] = 0;
    __syncthreads();
    int n = blockIdx.x * 256 + tid;
    int slot = -1, t = 0;
    if (n < N_NODES) {
        t = node_type[n];
        slot = atomicAdd(&lcur[t], 1);
    }
    __syncthreads();
    if (tid < 4) lbase[tid] = atomicAdd(&tb[4 + tid], lcur[tid]);
    __syncthreads();
    if (n < N_NODES) tlist[lbase[t] + slot] = n;
}

// ================= MFMA tiles =================
#define APAD 136

// ---------- fused: sort phase A (coarse bin) [0,FB) + hetero MFMA [FB, FB+4*NBH) ----------
__global__ void cg_sortA_hetero(const int* __restrict__ edge_index, const int* __restrict__ edge_type,
                                int* __restrict__ ccursor, int2* __restrict__ tmp2,
                                const unsigned short* __restrict__ xb,
                                const unsigned short* __restrict__ Wt,
                                const float* __restrict__ bhf,
                                const int* __restrict__ tlist, const int* __restrict__ tb,
                                unsigned short* __restrict__ h) {
    __shared__ unsigned short a_lds[64][APAD];
    __shared__ unsigned short b_lds[DIM][APAD];
    int bk = blockIdx.x;
    int tx = threadIdx.x;
    if (bk < FB) {
        __shared__ int lhist[NCB];
        __shared__ int lbase[NCB];
        for (int i = tx; i < NCB; i += 256) lhist[i] = 0;
        __syncthreads();
        int t = bk * 256 + tx;
        int d[4], cb[4], ls[4], pl[4];
        bool act = (t < EC);
        if (act) {
#pragma unroll
            for (int k = 0; k < 4; k++) {
                int e = t + k * EC;
                d[k]  = edge_index[N_EDGES + e];
                pl[k] = (edge_index[e] << 2) | edge_type[e];
                cb[k] = d[k] >> 8;
                ls[k] = atomicAdd(&lhist[cb[k]], 1);
            }
        }
        __syncthreads();
        for (int i = tx; i < NCB; i += 256)
            lbase[i] = lhist[i] ? atomicAdd(&ccursor[i], lhist[i]) : 0;
        __syncthreads();
        if (act) {
#pragma unroll
            for (int k = 0; k < 4; k++) {
                int pos = lbase[cb[k]] + ls[k];
                tmp2[pos] = make_int2(pl[k], d[k]);
            }
        }
        return;
    }
    int bb = bk - FB;
    int t    = bb / NBH;
    int nblk = bb - t * NBH;
    int rows_base = tb[8 + t] + nblk * 64;
    int rend = tb[8 + t + 1];
    if (rows_base >= rend) return;
    const unsigned short* Wsrc = Wt + (long)t * DIM * DIM;
    for (int i = tx; i < 2048; i += 256) {
        uint4 w = *(const uint4*)(Wsrc + i * 8);
        int o = i >> 4, d2 = (i & 15) * 8;
        *(uint4*)&b_lds[o][d2] = w;
    }
    for (int i = tx; i < 1024; i += 256) {
        int row = i >> 4, seg = (i & 15) * 8;
        int gr = rows_base + row;
        uint4 w = make_uint4(0u, 0u, 0u, 0u);
        if (gr < rend) {
            int n = tlist[gr];
            w = *(const uint4*)(xb + (long)n * DIM + seg);
        }
        *(uint4*)&a_lds[row][seg] = w;
    }
    __syncthreads();
    int wv = tx >> 6, lane = tx & 63;
    int m16 = lane & 15, quad = lane >> 4;
    f32x4 acc[8];
#pragma unroll
    for (int c = 0; c < 8; c++) acc[c] = (f32x4){0.f, 0.f, 0.f, 0.f};
    for (int ks = 0; ks < 4; ks++) {
        int koff = ks * 32 + quad * 8;
        bf16x8 af = *(const bf16x8*)(const void*)&a_lds[wv * 16 + m16][koff];
#pragma unroll
        for (int c = 0; c < 8; c++) {
            bf16x8 bfr = *(const bf16x8*)(const void*)&b_lds[c * 16 + m16][koff];
            acc[c] = __builtin_amdgcn_mfma_f32_16x16x32_bf16(af, bfr, acc[c], 0, 0, 0);
        }
    }
    __syncthreads();
#pragma unroll
    for (int c = 0; c < 8; c++) {
#pragma unroll
        for (int i = 0; i < 4; i++) {
            int row = wv * 16 + quad * 4 + i;
            int col = c * 16 + m16;
            a_lds[row][col] = f_to_bf16(acc[c][i] + bhf[t * DIM + col]);
        }
    }
    __syncthreads();
    for (int i = tx; i < 1024; i += 256) {
        int row = i >> 4, seg = (i & 15) * 8;
        int gr = rows_base + row;
        if (gr < rend) {
            int n = tlist[gr];
            *(uint4*)(h + (long)n * DIM + seg) = *(const uint4*)&a_lds[row][seg];
        }
    }
}

// ---------- fused: sort phase B (local count+scan -> rowptr + place) [0,NCB) + pgemm l=0 ----------
__global__ void cg_sortB_pgemm(const int2* __restrict__ tmp2, const int* __restrict__ blockoff,
                               int* __restrict__ rowptr, int* __restrict__ eidx,
                               const unsigned short* __restrict__ h,
                               const unsigned short* __restrict__ M2t,
                               unsigned short* __restrict__ P) {
    __shared__ unsigned short a_lds[64][APAD];
    __shared__ unsigned short b_lds[DIM][APAD];
    int bk = blockIdx.x;
    int tx = threadIdx.x;
    if (bk < NCB) {
        __shared__ int lcnt[256];
        __shared__ int lscan[256];
        __shared__ int lcur[256];
        lcnt[tx] = 0;
        int base = blockoff[bk];
        int endp = (bk + 1 < NCB) ? blockoff[bk + 1] : N_EDGES;
        int cnt = endp - base;
        __syncthreads();
        for (int i = tx; i < cnt; i += 256)
            atomicAdd(&lcnt[tmp2[base + i].y & 255], 1);
        __syncthreads();
        int v = lcnt[tx];
        lscan[tx] = v;
        __syncthreads();
        for (int off = 1; off < 256; off <<= 1) {
            int a = (tx >= off) ? lscan[tx - off] : 0;
            __syncthreads();
            lscan[tx] += a;
            __syncthreads();
        }
        int start = base + lscan[tx] - v;    // exclusive
        lcur[tx] = start;
        int n = bk * 256 + tx;
        if (n < N_NODES) rowptr[n] = start;
        __syncthreads();
        for (int i = tx; i < cnt; i += 256) {
            int2 e = tmp2[base + i];
            int pos = atomicAdd(&lcur[e.y & 255], 1);
            eidx[pos] = e.x;
        }
        return;
    }
    int bb = bk - NCB;
    int r    = bb / NBH;
    int nblk = bb - r * NBH;
    int n0 = nblk * 64;
    const unsigned short* Bsrc = M2t + (long)r * DIM * DIM;   // l = 0
    for (int i = tx; i < 2048; i += 256) {
        uint4 w = *(const uint4*)(Bsrc + i * 8);
        int o = i >> 4, d = (i & 15) * 8;
        *(uint4*)&b_lds[o][d] = w;
    }
    for (int i = tx; i < 1024; i += 256) {
        int row = i >> 4, seg = (i & 15) * 8;
        int n = n0 + row;
        uint4 w = make_uint4(0u, 0u, 0u, 0u);
        if (n < N_NODES) w = *(const uint4*)(h + (long)n * DIM + seg);
        *(uint4*)&a_lds[row][seg] = w;
    }
    __syncthreads();
    int wv = tx >> 6, lane = tx & 63;
    int m16 = lane & 15, quad = lane >> 4;
    f32x4 acc[8];
#pragma unroll
    for (int c = 0; c < 8; c++) acc[c] = (f32x4){0.f, 0.f, 0.f, 0.f};
    for (int ks = 0; ks < 4; ks++) {
        int koff = ks * 32 + quad * 8;
        bf16x8 af = *(const bf16x8*)(const void*)&a_lds[wv * 16 + m16][koff];
#pragma unroll
        for (int c = 0; c < 8; c++) {
            bf16x8 bfr = *(const bf16x8*)(const void*)&b_lds[c * 16 + m16][koff];
            acc[c] = __builtin_amdgcn_mfma_f32_16x16x32_bf16(af, bfr, acc[c], 0, 0, 0);
        }
    }
    __syncthreads();
#pragma unroll
    for (int c = 0; c < 8; c++) {
#pragma unroll
        for (int i = 0; i < 4; i++) {
            int row = wv * 16 + quad * 4 + i;
            int col = c * 16 + m16;
            a_lds[row][col] = f_to_bf16(acc[c][i]);
        }
    }
    __syncthreads();
    for (int i = tx; i < 1024; i += 256) {
        int row = i >> 4, seg = (i & 15) * 8;
        int n = n0 + row;
        if (n < N_NODES)
            *(uint4*)(P + (long)n * (RR * DIM) + r * DIM + seg) = *(const uint4*)&a_lds[row][seg];
    }
}

// ---------- fused: gather(l0 from P0) + pgemm(l1) -> P1.  one block = 64 nodes ----------
__global__ void cg_gather_pgemm(const unsigned short* __restrict__ P0,
                                const int* __restrict__ rowptr, const int* __restrict__ eidx,
                                const float* __restrict__ cv0,
                                const unsigned short* __restrict__ M2t,   // l=1 base
                                unsigned short* __restrict__ P1) {
    __shared__ unsigned short a_lds[64][APAD];
    __shared__ unsigned short b_lds[DIM][APAD];
    int n0 = blockIdx.x * 64;
    int tx = threadIdx.x;
    int wv = tx >> 6, lane = tx & 63;
    int eg = lane >> 4;
    int ol = lane & 15;
    // phase 1: each wave gathers 16 nodes (rows wv*16 .. +15) into a_lds
    for (int rr = 0; rr < 16; rr++) {
        int row = wv * 16 + rr;
        int n = n0 + row;
        float a[8] = {0.f, 0.f, 0.f, 0.f, 0.f, 0.f, 0.f, 0.f};
        if (n < N_NODES) {
            int start = rowptr[n];
            int end   = (n + 1 < N_NODES) ? rowptr[n + 1] : N_EDGES;
            int j = start + eg;
            for (; j + 4 < end; j += 8) {
                int v0 = eidx[j];
                int v1 = eidx[j + 4];
                const uint4 w0 = *(const uint4*)(P0 + (long)(v0 >> 2) * (RR * DIM) + (v0 & 3) * DIM + ol * 8);
                const uint4 w1 = *(const uint4*)(P0 + (long)(v1 >> 2) * (RR * DIM) + (v1 & 3) * DIM + ol * 8);
                a[0] += bf16_to_f((unsigned short)(w0.x & 0xFFFFu)) + bf16_to_f((unsigned short)(w1.x & 0xFFFFu));
                a[1] += bf16_to_f((unsigned short)(w0.x >> 16))     + bf16_to_f((unsigned short)(w1.x >> 16));
                a[2] += bf16_to_f((unsigned short)(w0.y & 0xFFFFu)) + bf16_to_f((unsigned short)(w1.y & 0xFFFFu));
                a[3] += bf16_to_f((unsigned short)(w0.y >> 16))     + bf16_to_f((unsigned short)(w1.y >> 16));
                a[4] += bf16_to_f((unsigned short)(w0.z & 0xFFFFu)) + bf16_to_f((unsigned short)(w1.z & 0xFFFFu));
                a[5] += bf16_to_f((unsigned short)(w0.z >> 16))     + bf16_to_f((unsigned short)(w1.z >> 16));
                a[6] += bf16_to_f((unsigned short)(w0.w & 0xFFFFu)) + bf16_to_f((unsigned short)(w1.w & 0xFFFFu));
                a[7] += bf16_to_f((unsigned short)(w0.w >> 16))     + bf16_to_f((unsigned short)(w1.w >> 16));
            }
            if (j < end) {
                int v = eidx[j];
                const uint4 w = *(const uint4*)(P0 + (long)(v >> 2) * (RR * DIM) + (v & 3) * DIM + ol * 8);
                a[0] += bf16_to_f((unsigned short)(w.x & 0xFFFFu));
                a[1] += bf16_to_f((unsigned short)(w.x >> 16));
                a[2] += bf16_to_f((unsigned short)(w.y & 0xFFFFu));
                a[3] += bf16_to_f((unsigned short)(w.y >> 16));
                a[4] += bf16_to_f((unsigned short)(w.z & 0xFFFFu));
                a[5] += bf16_to_f((unsigned short)(w.z >> 16));
                a[6] += bf16_to_f((unsigned short)(w.w & 0xFFFFu));
                a[7] += bf16_to_f((unsigned short)(w.w >> 16));
            }
        }
#pragma unroll
        for (int i = 0; i < 8; i++) {
            a[i] += __shfl_xor(a[i], 16);
            a[i] += __shfl_xor(a[i], 32);
        }
        if (eg == 0) {
            int o0 = ol * 8;
            uint4 o4;
            float v0 = a[0] + cv0[o0 + 0]; v0 = v0 > 0.f ? v0 : 0.f;
            float v1 = a[1] + cv0[o0 + 1]; v1 = v1 > 0.f ? v1 : 0.f;
            float v2 = a[2] + cv0[o0 + 2]; v2 = v2 > 0.f ? v2 : 0.f;
            float v3 = a[3] + cv0[o0 + 3]; v3 = v3 > 0.f ? v3 : 0.f;
            float v4 = a[4] + cv0[o0 + 4]; v4 = v4 > 0.f ? v4 : 0.f;
            float v5 = a[5] + cv0[o0 + 5]; v5 = v5 > 0.f ? v5 : 0.f;
            float v6 = a[6] + cv0[o0 + 6]; v6 = v6 > 0.f ? v6 : 0.f;
            float v7 = a[7] + cv0[o0 + 7]; v7 = v7 > 0.f ? v7 : 0.f;
            o4.x = (unsigned int)f_to_bf16(v0) | ((unsigned int)f_to_bf16(v1) << 16);
            o4.y = (unsigned int)f_to_bf16(v2) | ((unsigned int)f_to_bf16(v3) << 16);
            o4.z = (unsigned int)f_to_bf16(v4) | ((unsigned int)f_to_bf16(v5) << 16);
            o4.w = (unsigned int)f_to_bf16(v6) | ((unsigned int)f_to_bf16(v7) << 16);
            *(uint4*)&a_lds[row][o0] = o4;
        }
    }
    __syncthreads();
    // phase 2: loop r, stage B = M2t[l=1][r], MFMA resident A, write P1
    int m16 = lane & 15, quad = lane >> 4;
    for (int r = 0; r < RR; r++) {
        const unsigned short* Bsrc = M2t + (long)(RR + r) * DIM * DIM;   // l = 1
        for (int i = tx; i < 2048; i += 256) {
            uint4 w = *(const uint4*)(Bsrc + i * 8);
            int o = i >> 4, d = (i & 15) * 8;
            *(uint4*)&b_lds[o][d] = w;
        }
        __syncthreads();
        f32x4 acc[8];
#pragma unroll
        for (int c = 0; c < 8; c++) acc[c] = (f32x4){0.f, 0.f, 0.f, 0.f};
        for (int ks = 0; ks < 4; ks++) {
            int koff = ks * 32 + quad * 8;
            bf16x8 af = *(const bf16x8*)(const void*)&a_lds[wv * 16 + m16][koff];
#pragma unroll
            for (int c = 0; c < 8; c++) {
                bf16x8 bfr = *(const bf16x8*)(const void*)&b_lds[c * 16 + m16][koff];
                acc[c] = __builtin_amdgcn_mfma_f32_16x16x32_bf16(af, bfr, acc[c], 0, 0, 0);
            }
        }
        __syncthreads();   // MFMA reads of b_lds done; reuse b_lds for epilogue transpose
#pragma unroll
        for (int c = 0; c < 8; c++) {
#pragma unroll
            for (int i = 0; i < 4; i++) {
                int row = wv * 16 + quad * 4 + i;
                int col = c * 16 + m16;
                b_lds[row][col] = f_to_bf16(acc[c][i]);
            }
        }
        __syncthreads();
        for (int i = tx; i < 1024; i += 256) {
            int row = i >> 4, seg = (i & 15) * 8;
            int n = n0 + row;
            if (n < N_NODES)
                *(uint4*)(P1 + (long)n * (RR * DIM) + r * DIM + seg) = *(const uint4*)&b_lds[row][seg];
        }
        __syncthreads();   // epilogue reads done before next r's staging overwrites b_lds
    }
}

// ---------- gather (final layer): P1 -> hbf ----------
__global__ void cg_gather4(const unsigned short* __restrict__ P, const int* __restrict__ rowptr,
                           const int* __restrict__ eidx, const float* __restrict__ cv,
                           unsigned short* __restrict__ hout) {
    int wid  = (blockIdx.x * 256 + threadIdx.x) >> 6;
    int lane = threadIdx.x & 63;
    if (wid >= N_NODES) return;
    int eg = lane >> 4;
    int ol = lane & 15;
    int start = rowptr[wid];
    int end   = (wid + 1 < N_NODES) ? rowptr[wid + 1] : N_EDGES;
    float a[8] = {0.f, 0.f, 0.f, 0.f, 0.f, 0.f, 0.f, 0.f};
    int j = start + eg;
    for (; j + 4 < end; j += 8) {
        int v0 = eidx[j];
        int v1 = eidx[j + 4];
        const uint4 w0 = *(const uint4*)(P + (long)(v0 >> 2) * (RR * DIM) + (v0 & 3) * DIM + ol * 8);
        const uint4 w1 = *(const uint4*)(P + (long)(v1 >> 2) * (RR * DIM) + (v1 & 3) * DIM + ol * 8);
        a[0] += bf16_to_f((unsigned short)(w0.x & 0xFFFFu)) + bf16_to_f((unsigned short)(w1.x & 0xFFFFu));
        a[1] += bf16_to_f((unsigned short)(w0.x >> 16))     + bf16_to_f((unsigned short)(w1.x >> 16));
        a[2] += bf16_to_f((unsigned short)(w0.y & 0xFFFFu)) + bf16_to_f((unsigned short)(w1.y & 0xFFFFu));
        a[3] += bf16_to_f((unsigned short)(w0.y >> 16))     + bf16_to_f((unsigned short)(w1.y >> 16));
        a[4] += bf16_to_f((unsigned short)(w0.z & 0xFFFFu)) + bf16_to_f((unsigned short)(w1.z & 0xFFFFu));
        a[5] += bf16_to_f((unsigned short)(w0.z >> 16))     + bf16_to_f((unsigned short)(w1.z >> 16));
        a[6] += bf16_to_f((unsigned short)(w0.w & 0xFFFFu)) + bf16_to_f((unsigned short)(w1.w & 0xFFFFu));
        a[7] += bf16_to_f((unsigned short)(w0.w >> 16))     + bf16_to_f((unsigned short)(w1.w >> 16));
    }
    if (j < end) {
        int v = eidx[j];
        const uint4 w = *(const uint4*)(P + (long)(v >> 2) * (RR * DIM) + (v & 3) * DIM + ol * 8);
        a[0] += bf16_to_f((unsigned short)(w.x & 0xFFFFu));
        a[1] += bf16_to_f((unsigned short)(w.x >> 16));
        a[2] += bf16_to_f((unsigned short)(w.y & 0xFFFFu));
        a[3] += bf16_to_f((unsigned short)(w.y >> 16));
        a[4] += bf16_to_f((unsigned short)(w.z & 0xFFFFu));
        a[5] += bf16_to_f((unsigned short)(w.z >> 16));
        a[6] += bf16_to_f((unsigned short)(w.w & 0xFFFFu));
        a[7] += bf16_to_f((unsigned short)(w.w >> 16));
    }
#pragma unroll
    for (int i = 0; i < 8; i++) {
        a[i] += __shfl_xor(a[i], 16);
        a[i] += __shfl_xor(a[i], 32);
    }
    if (eg == 0) {
        int o0 = ol * 8;
        float v[8];
#pragma unroll
        for (int i = 0; i < 8; i++) {
            float s = a[i] + cv[o0 + i];
            v[i] = s > 0.0f ? s : 0.0f;
        }
        uint4 o4;
        o4.x = (unsigned int)f_to_bf16(v[0]) | ((unsigned int)f_to_bf16(v[1]) << 16);
        o4.y = (unsigned int)f_to_bf16(v[2]) | ((unsigned int)f_to_bf16(v[3]) << 16);
        o4.z = (unsigned int)f_to_bf16(v[4]) | ((unsigned int)f_to_bf16(v[5]) << 16);
        o4.w = (unsigned int)f_to_bf16(v[6]) | ((unsigned int)f_to_bf16(v[7]) << 16);
        *(uint4*)(hout + (long)wid * DIM + o0) = o4;
    }
}

// ---------- fused mean-pool + logits: one block per graph ----------
__global__ void cg_pool_logits(const unsigned short* __restrict__ h, const int* __restrict__ batch,
                               const void* __restrict__ cls_W, const void* __restrict__ cls_b,
                               const int* __restrict__ flagp, void* __restrict__ out) {
    __shared__ float acc_s[4][DIM];
    __shared__ float emb_s[DIM];
    int g   = blockIdx.x;
    int tid = threadIdx.x;
    int wv  = tid >> 6;
    int lane = tid & 63;
    int sub = lane >> 4;
    int ol  = lane & 15;
    int isbf = *flagp;
    int lo = 0, hi = N_NODES;
    while (lo < hi) { int mid = (lo + hi) >> 1; if (batch[mid] < g) lo = mid + 1; else hi = mid; }
    int start = lo;
    hi = N_NODES;
    while (lo < hi) { int mid = (lo + hi) >> 1; if (batch[mid] < g + 1) lo = mid + 1; else hi = mid; }
    int end = lo;
    float a[8] = {0.f, 0.f, 0.f, 0.f, 0.f, 0.f, 0.f, 0.f};
    for (int n = start + wv * 4 + sub; n < end; n += 16) {
        uint4 w = *(const uint4*)(h + (long)n * DIM + ol * 8);
        a[0] += bf16_to_f((unsigned short)(w.x & 0xFFFFu));
        a[1] += bf16_to_f((unsigned short)(w.x >> 16));
        a[2] += bf16_to_f((unsigned short)(w.y & 0xFFFFu));
        a[3] += bf16_to_f((unsigned short)(w.y >> 16));
        a[4] += bf16_to_f((unsigned short)(w.z & 0xFFFFu));
        a[5] += bf16_to_f((unsigned short)(w.z >> 16));
        a[6] += bf16_to_f((unsigned short)(w.w & 0xFFFFu));
        a[7] += bf16_to_f((unsigned short)(w.w >> 16));
    }
#pragma unroll
    for (int i = 0; i < 8; i++) {
        a[i] += __shfl_xor(a[i], 16);
        a[i] += __shfl_xor(a[i], 32);
    }
    if (sub == 0) {
#pragma unroll
        for (int i = 0; i < 8; i++) acc_s[wv][ol * 8 + i] = a[i];
    }
    __syncthreads();
    int cnt = end - start;
    float inv = 1.0f / (float)(cnt > 1 ? cnt : 1);
    if (tid < DIM) {
        float e = (acc_s[0][tid] + acc_s[1][tid] + acc_s[2][tid] + acc_s[3][tid]) * inv;
        emb_s[tid] = e;
        storef(out, (long)g * DIM + tid, e, isbf);
    }
    __syncthreads();
    if (tid < 128) {
        int c  = tid >> 4;
        int kk = tid & 15;
        float p = 0.0f;
#pragma unroll
        for (int k = kk * 8; k < kk * 8 + 8; k++)
            p += emb_s[k] * loadf(cls_W, (long)k * CC + c, isbf);
        p += __shfl_xor(p, 1);
        p += __shfl_xor(p, 2);
        p += __shfl_xor(p, 4);
        p += __shfl_xor(p, 8);
        if (kk == 0)
            storef(out, (long)GG * DIM + g * CC + c, p + loadf(cls_b, c, isbf), isbf);
    }
}

extern "C" void kernel_launch(void* const* d_in, const int* in_sizes, int n_in,
                              void* d_out, int out_size, void* d_ws, size_t ws_size,
                              hipStream_t stream) {
    const void* x      = d_in[0];
    const void* W_het  = d_in[1];
    const void* b_het  = d_in[2];
    const void* conv_W = d_in[3];
    const void* conv_b = d_in[4];
    const void* fuse_W = d_in[5];
    const void* fuse_b = d_in[6];
    const void* cls_W  = d_in[7];
    const void* cls_b  = d_in[8];
    const int* node_type  = (const int*)d_in[9];
    const int* edge_index = (const int*)d_in[10];
    const int* edge_type  = (const int*)d_in[11];
    const int* batch      = (const int*)d_in[12];

    // workspace layout (bytes, 16B aligned; ws_size ~268 MB per harness fills)
    char* base = (char*)d_ws;
    unsigned short* hbf      = (unsigned short*)(base + 0);          // 12,800,000
    unsigned short* P0       = (unsigned short*)(base + 12800000);   // 51,200,000
    unsigned short* xb       = (unsigned short*)(base + 64000000);   // 12,800,000
    unsigned short* Wt       = (unsigned short*)(base + 76800000);   //    131,072
    float*          bhf      = (float*)(base + 76931072);            //      2,048
    unsigned short* M2t      = (unsigned short*)(base + 76933120);   //    262,144
    float*          cvec     = (float*)(base + 77195264);            //      1,024
    int*            rowptr   = (int*)(base + 77196288);              //    200,032
    int*            chist    = (int*)(base + 77396320);              //  chist[196]+tb[16]
    int*            tb       = chist + NCB;
    int*            blockoff = (int*)(base + 77397408);              //      1,024
    int*            ccursor  = (int*)(base + 77398432);              //      1,024
    int*            eidx     = (int*)(base + 77399456);              //  2,400,000
    int*            tlist    = (int*)(base + 79799456);              //    200,000
    int*            flag     = (int*)(base + 79999456);              //          4
    int2*           tmp2     = (int2*)(base + 79999472);             //  4,800,000
    unsigned short* P1       = (unsigned short*)(base + 84799472);   // 51,200,000 (total ~136 MB)

    cg_init<<<1, 256, 0, stream>>>((const unsigned int*)x, flag, chist);
    cg_hist_canon<<<FB + CB, 256, 0, stream>>>(edge_index, node_type, chist, tb,
                                               x, W_het, b_het, conv_W, fuse_W,
                                               conv_b, fuse_b, flag,
                                               xb, Wt, bhf, M2t, cvec);
    cg_scan196<<<1, 256, 0, stream>>>(chist, blockoff, ccursor, tb);
    cg_tfill<<<TB, 256, 0, stream>>>(node_type, tb, tlist);
    cg_sortA_hetero<<<FB + 4 * NBH, 256, 0, stream>>>(edge_index, edge_type, ccursor, tmp2,
                                                      xb, Wt, bhf, tlist, tb, hbf);
    cg_sortB_pgemm<<<NCB + 4 * NBH, 256, 0, stream>>>(tmp2, blockoff, rowptr, eidx,
                                                      hbf, M2t, P0);
    cg_gather_pgemm<<<NBH, 256, 0, stream>>>(P0, rowptr, eidx, cvec, M2t, P1);
    cg_gather4<<<(N_NODES * 64 + 255) / 256, 256, 0, stream>>>(
        P1, rowptr, eidx, cvec + DIM, hbf);
    cg_pool_logits<<<GG, 256, 0, stream>>>(hbf, batch, cls_W, cls_b, flag, d_out);
}

// Round 20
// 291.265 us; speedup vs baseline: 1.1647x; 1.1647x over previous
//
#include <hip/hip_runtime.h>

#define N_NODES 50000
#define N_EDGES 600000
#define DIM     128
#define RR      4
#define LL      2
#define GG      512
#define CC      8
#define NCB     196                       // coarse buckets (nodes >> 8)
#define EC      (N_EDGES / 4)             // 150000
#define FB      ((EC + 255) / 256)        // 586 hist/sortA blocks
#define TB      ((N_NODES + 255) / 256)   // 196 tfill blocks
#define NBH     ((N_NODES + 63) / 64)     // 782 MFMA tile blocks
#define CB      (1026 + 3125)             // 4151 canon blocks

typedef short bf16x8 __attribute__((ext_vector_type(8)));
typedef float f32x4  __attribute__((ext_vector_type(4)));

// ---------- bf16 <-> f32 helpers ----------
__device__ __forceinline__ float bf16_to_f(unsigned short u) {
    return __uint_as_float(((unsigned int)u) << 16);
}
__device__ __forceinline__ unsigned short f_to_bf16(float f) {
    unsigned int u = __float_as_uint(f);
    u += 0x7FFFu + ((u >> 16) & 1u);   // RNE
    return (unsigned short)(u >> 16);
}
__device__ __forceinline__ float loadf(const void* p, long i, int isbf) {
    if (isbf) return bf16_to_f(((const unsigned short*)p)[i]);
    return ((const float*)p)[i];
}
__device__ __forceinline__ void storef(void* p, long i, float v, int isbf) {
    if (isbf) ((unsigned short*)p)[i] = f_to_bf16(v);
    else      ((float*)p)[i] = v;
}

// ---------- init: zero chist(196)+tb(16), dtype-detect. one block ----------
__global__ void cg_init(const unsigned int* __restrict__ xw, int* __restrict__ flag,
                        int* __restrict__ chist_tb) {
    __shared__ int cnt;
    int tid = threadIdx.x;
    if (tid < NCB + 16) chist_tb[tid] = 0;
    if (tid == 0) cnt = 0;
    __syncthreads();
    unsigned int w = xw[tid];
    unsigned int e = (w >> 7) & 0xFFu;
    atomicAdd(&cnt, (e >= 110u && e <= 133u) ? 1 : 0);
    __syncthreads();
    if (tid == 0) *flag = (cnt >= 128) ? 1 : 0;
}

// ---------- fused: coarse-bucket + node-type histograms [0,FB) + canonicalization ----------
__global__ void cg_hist_canon(const int* __restrict__ edge_index, const int* __restrict__ node_type,
                              int* __restrict__ chist, int* __restrict__ tb,
                              const void* __restrict__ x,
                              const void* __restrict__ W_het, const void* __restrict__ b_het,
                              const void* __restrict__ conv_W, const void* __restrict__ fuse_W,
                              const void* __restrict__ conv_b, const void* __restrict__ fuse_b,
                              const int* __restrict__ flagp,
                              unsigned short* __restrict__ xb, unsigned short* __restrict__ Wt,
                              float* __restrict__ bhf,
                              unsigned short* __restrict__ M2t, float* __restrict__ cvec) {
    __shared__ float s[256];
    int bk = blockIdx.x;
    int tid = threadIdx.x;
    if (bk < FB) {
        __shared__ int lh[NCB];
        __shared__ int loc[4];
        for (int i = tid; i < NCB; i += 256) lh[i] = 0;
        if (tid < 4) loc[tid] = 0;
        __syncthreads();
        int t = bk * 256 + tid;
        if (t < EC) {
#pragma unroll
            for (int k = 0; k < 4; k++) {
                int d = edge_index[N_EDGES + t + k * EC];
                atomicAdd(&lh[d >> 8], 1);
            }
        }
        if (t < N_NODES) atomicAdd(&loc[node_type[t]], 1);
        __syncthreads();
        for (int i = tid; i < NCB; i += 256)
            if (lh[i]) atomicAdd(&chist[i], lh[i]);
        if (tid < 4 && loc[tid]) atomicAdd(&tb[tid], loc[tid]);
        return;
    }
    int b = bk - FB;
    int isbf = *flagp;
    if (b < 512) {                      // M2t: 2 d-rows per block
        int lr = b >> 6;
        int d  = (b & 63) * 2 + (tid >> 7);
        int r  = lr & 3;
        int o  = tid & 127;
        float acc = 0.0f;
        for (int k = 0; k < DIM; k++) {
            acc += loadf(conv_W, (long)(lr * DIM + d) * DIM + k, isbf)
                 * loadf(fuse_W, (long)(r * DIM + k) * DIM + o, isbf);
        }
        M2t[((long)lr * DIM + o) * DIM + d] = f_to_bf16(acc);
    } else if (b < 768) {               // cvec
        int bc = b - 512;
        int l  = bc >> 7;
        int o  = bc & 127;
        float part = 0.0f;
        for (int rk = tid; rk < RR * DIM; rk += 256) {
            part += loadf(conv_b, (long)l * RR * DIM + rk, isbf)
                  * loadf(fuse_W, (long)rk * DIM + o, isbf);
        }
        s[tid] = part;
        __syncthreads();
        for (int off = 128; off > 0; off >>= 1) {
            if (tid < off) s[tid] += s[tid + off];
            __syncthreads();
        }
        if (tid == 0) cvec[bc] = s[0] + loadf(fuse_b, o, isbf);
    } else if (b < 1024) {              // Wt[t][o][d]; 2 (t,o) per block
        int pair = (b - 768) * 2 + (tid >> 7);
        int t = pair >> 7;
        int o = pair & 127;
        int d = tid & 127;
        float v = loadf(W_het, ((long)t * DIM + d) * DIM + o, isbf);
        Wt[((long)t * DIM + o) * DIM + d] = f_to_bf16(v);
    } else if (b < 1026) {              // bhf
        int idx = (b - 1024) * 256 + tid;
        if (idx < 4 * DIM) bhf[idx] = loadf(b_het, idx, isbf);
    } else {                            // xb: 8 elems/thread
        long i = ((long)(b - 1026) * 256 + tid) * 8;
        if (i >= (long)N_NODES * DIM) return;
        if (isbf) {
            *(uint4*)(xb + i) = *(const uint4*)((const unsigned short*)x + i);
        } else {
            const float* xf = (const float*)x + i;
            float4 f0 = *(const float4*)xf;
            float4 f1 = *(const float4*)(xf + 4);
            uint4 o;
            o.x = (unsigned int)f_to_bf16(f0.x) | ((unsigned int)f_to_bf16(f0.y) << 16);
            o.y = (unsigned int)f_to_bf16(f0.z) | ((unsigned int)f_to_bf16(f0.w) << 16);
            o.z = (unsigned int)f_to_bf16(f1.x) | ((unsigned int)f_to_bf16(f1.y) << 16);
            o.w = (unsigned int)f_to_bf16(f1.z) | ((unsigned int)f_to_bf16(f1.w) << 16);
            *(uint4*)(xb + i) = o;
        }
    }
}

// ---------- single-block: scan coarse hist -> blockoff/ccursor; scan tb ----------
__global__ void cg_scan196(const int* __restrict__ chist, int* __restrict__ blockoff,
                           int* __restrict__ ccursor, int* __restrict__ tb) {
    __shared__ int s[256];
    int tid = threadIdx.x;
    int v = (tid < NCB) ? chist[tid] : 0;
    s[tid] = v;
    __syncthreads();
    for (int off = 1; off < 256; off <<= 1) {
        int a = (tid >= off) ? s[tid - off] : 0;
        __syncthreads();
        s[tid] += a;
        __syncthreads();
    }
    if (tid < NCB) {
        int e = s[tid] - v;            // exclusive bucket start
        blockoff[tid] = e;
        ccursor[tid]  = e;
    }
    if (tid == 0) {
        int run = 0;
        for (int t = 0; t < 4; t++) {
            tb[8 + t] = run;
            tb[4 + t] = run;
            run += tb[t];
        }
        tb[12] = run;
    }
}

// ---------- node-type list fill (block-aggregated) ----------
__global__ void cg_tfill(const int* __restrict__ node_type, int* __restrict__ tb,
                         int* __restrict__ tlist) {
    __shared__ int lcur[4];
    __shared__ int lbase[4];
    int tid = threadIdx.x;
    if (tid < 4) lcur[tid] = 0;
    __syncthreads();
    int n = blockIdx.x * 256 + tid;
    int slot = -1, t = 0;
    if (n < N_NODES) {
        t = node_type[n];
        slot = atomicAdd(&lcur[t], 1);
    }
    __syncthreads();
    if (tid < 4) lbase[tid] = atomicAdd(&tb[4 + tid], lcur[tid]);
    __syncthreads();
    if (n < N_NODES) tlist[lbase[t] + slot] = n;
}

// ================= MFMA tiles =================
#define APAD 136

// ---------- fused: sort phase A (coarse bin) [0,FB) + hetero MFMA [FB, FB+4*NBH) ----------
__global__ void cg_sortA_hetero(const int* __restrict__ edge_index, const int* __restrict__ edge_type,
                                int* __restrict__ ccursor, int2* __restrict__ tmp2,
                                const unsigned short* __restrict__ xb,
                                const unsigned short* __restrict__ Wt,
                                const float* __restrict__ bhf,
                                const int* __restrict__ tlist, const int* __restrict__ tb,
                                unsigned short* __restrict__ h) {
    __shared__ unsigned short a_lds[64][APAD];
    __shared__ unsigned short b_lds[DIM][APAD];
    int bk = blockIdx.x;
    int tx = threadIdx.x;
    if (bk < FB) {
        __shared__ int lhist[NCB];
        __shared__ int lbase[NCB];
        for (int i = tx; i < NCB; i += 256) lhist[i] = 0;
        __syncthreads();
        int t = bk * 256 + tx;
        int d[4], cb[4], ls[4], pl[4];
        bool act = (t < EC);
        if (act) {
#pragma unroll
            for (int k = 0; k < 4; k++) {
                int e = t + k * EC;
                d[k]  = edge_index[N_EDGES + e];
                pl[k] = (edge_index[e] << 2) | edge_type[e];
                cb[k] = d[k] >> 8;
                ls[k] = atomicAdd(&lhist[cb[k]], 1);
            }
        }
        __syncthreads();
        for (int i = tx; i < NCB; i += 256)
            lbase[i] = lhist[i] ? atomicAdd(&ccursor[i], lhist[i]) : 0;
        __syncthreads();
        if (act) {
#pragma unroll
            for (int k = 0; k < 4; k++) {
                int pos = lbase[cb[k]] + ls[k];
                tmp2[pos] = make_int2(pl[k], d[k]);
            }
        }
        return;
    }
    int bb = bk - FB;
    int t    = bb / NBH;
    int nblk = bb - t * NBH;
    int rows_base = tb[8 + t] + nblk * 64;
    int rend = tb[8 + t + 1];
    if (rows_base >= rend) return;
    const unsigned short* Wsrc = Wt + (long)t * DIM * DIM;
    for (int i = tx; i < 2048; i += 256) {
        uint4 w = *(const uint4*)(Wsrc + i * 8);
        int o = i >> 4, d2 = (i & 15) * 8;
        *(uint4*)&b_lds[o][d2] = w;
    }
    for (int i = tx; i < 1024; i += 256) {
        int row = i >> 4, seg = (i & 15) * 8;
        int gr = rows_base + row;
        uint4 w = make_uint4(0u, 0u, 0u, 0u);
        if (gr < rend) {
            int n = tlist[gr];
            w = *(const uint4*)(xb + (long)n * DIM + seg);
        }
        *(uint4*)&a_lds[row][seg] = w;
    }
    __syncthreads();
    int wv = tx >> 6, lane = tx & 63;
    int m16 = lane & 15, quad = lane >> 4;
    f32x4 acc[8];
#pragma unroll
    for (int c = 0; c < 8; c++) acc[c] = (f32x4){0.f, 0.f, 0.f, 0.f};
    for (int ks = 0; ks < 4; ks++) {
        int koff = ks * 32 + quad * 8;
        bf16x8 af = *(const bf16x8*)(const void*)&a_lds[wv * 16 + m16][koff];
#pragma unroll
        for (int c = 0; c < 8; c++) {
            bf16x8 bfr = *(const bf16x8*)(const void*)&b_lds[c * 16 + m16][koff];
            acc[c] = __builtin_amdgcn_mfma_f32_16x16x32_bf16(af, bfr, acc[c], 0, 0, 0);
        }
    }
    __syncthreads();
#pragma unroll
    for (int c = 0; c < 8; c++) {
#pragma unroll
        for (int i = 0; i < 4; i++) {
            int row = wv * 16 + quad * 4 + i;
            int col = c * 16 + m16;
            a_lds[row][col] = f_to_bf16(acc[c][i] + bhf[t * DIM + col]);
        }
    }
    __syncthreads();
    for (int i = tx; i < 1024; i += 256) {
        int row = i >> 4, seg = (i & 15) * 8;
        int gr = rows_base + row;
        if (gr < rend) {
            int n = tlist[gr];
            *(uint4*)(h + (long)n * DIM + seg) = *(const uint4*)&a_lds[row][seg];
        }
    }
}

// ---------- fused: sort phase B (local count+scan -> rowptr + place) [0,NCB) + pgemm l=0 ----------
__global__ void cg_sortB_pgemm(const int2* __restrict__ tmp2, const int* __restrict__ blockoff,
                               int* __restrict__ rowptr, int* __restrict__ eidx,
                               const unsigned short* __restrict__ h,
                               const unsigned short* __restrict__ M2t,
                               unsigned short* __restrict__ P) {
    __shared__ unsigned short a_lds[64][APAD];
    __shared__ unsigned short b_lds[DIM][APAD];
    int bk = blockIdx.x;
    int tx = threadIdx.x;
    if (bk < NCB) {
        __shared__ int lcnt[256];
        __shared__ int lscan[256];
        __shared__ int lcur[256];
        lcnt[tx] = 0;
        int base = blockoff[bk];
        int endp = (bk + 1 < NCB) ? blockoff[bk + 1] : N_EDGES;
        int cnt = endp - base;
        __syncthreads();
        for (int i = tx; i < cnt; i += 256)
            atomicAdd(&lcnt[tmp2[base + i].y & 255], 1);
        __syncthreads();
        int v = lcnt[tx];
        lscan[tx] = v;
        __syncthreads();
        for (int off = 1; off < 256; off <<= 1) {
            int a = (tx >= off) ? lscan[tx - off] : 0;
            __syncthreads();
            lscan[tx] += a;
            __syncthreads();
        }
        int start = base + lscan[tx] - v;    // exclusive
        lcur[tx] = start;
        int n = bk * 256 + tx;
        if (n < N_NODES) rowptr[n] = start;
        __syncthreads();
        for (int i = tx; i < cnt; i += 256) {
            int2 e = tmp2[base + i];
            int pos = atomicAdd(&lcur[e.y & 255], 1);
            eidx[pos] = e.x;
        }
        return;
    }
    int bb = bk - NCB;
    int r    = bb / NBH;
    int nblk = bb - r * NBH;
    int n0 = nblk * 64;
    const unsigned short* Bsrc = M2t + (long)r * DIM * DIM;   // l = 0
    for (int i = tx; i < 2048; i += 256) {
        uint4 w = *(const uint4*)(Bsrc + i * 8);
        int o = i >> 4, d = (i & 15) * 8;
        *(uint4*)&b_lds[o][d] = w;
    }
    for (int i = tx; i < 1024; i += 256) {
        int row = i >> 4, seg = (i & 15) * 8;
        int n = n0 + row;
        uint4 w = make_uint4(0u, 0u, 0u, 0u);
        if (n < N_NODES) w = *(const uint4*)(h + (long)n * DIM + seg);
        *(uint4*)&a_lds[row][seg] = w;
    }
    __syncthreads();
    int wv = tx >> 6, lane = tx & 63;
    int m16 = lane & 15, quad = lane >> 4;
    f32x4 acc[8];
#pragma unroll
    for (int c = 0; c < 8; c++) acc[c] = (f32x4){0.f, 0.f, 0.f, 0.f};
    for (int ks = 0; ks < 4; ks++) {
        int koff = ks * 32 + quad * 8;
        bf16x8 af = *(const bf16x8*)(const void*)&a_lds[wv * 16 + m16][koff];
#pragma unroll
        for (int c = 0; c < 8; c++) {
            bf16x8 bfr = *(const bf16x8*)(const void*)&b_lds[c * 16 + m16][koff];
            acc[c] = __builtin_amdgcn_mfma_f32_16x16x32_bf16(af, bfr, acc[c], 0, 0, 0);
        }
    }
    __syncthreads();
#pragma unroll
    for (int c = 0; c < 8; c++) {
#pragma unroll
        for (int i = 0; i < 4; i++) {
            int row = wv * 16 + quad * 4 + i;
            int col = c * 16 + m16;
            a_lds[row][col] = f_to_bf16(acc[c][i]);
        }
    }
    __syncthreads();
    for (int i = tx; i < 1024; i += 256) {
        int row = i >> 4, seg = (i & 15) * 8;
        int n = n0 + row;
        if (n < N_NODES)
            *(uint4*)(P + (long)n * (RR * DIM) + r * DIM + seg) = *(const uint4*)&a_lds[row][seg];
    }
}

// ---------- pgemm (plain, for l=1) ----------
__global__ void cg_pgemm_mfma(const unsigned short* __restrict__ h,
                              const unsigned short* __restrict__ M2t, int l,
                              unsigned short* __restrict__ P) {
    int r  = blockIdx.y;
    int n0 = blockIdx.x * 64;
    __shared__ unsigned short a_lds[64][APAD];
    __shared__ unsigned short b_lds[DIM][APAD];
    int tx = threadIdx.x;
    const unsigned short* Bsrc = M2t + (long)(l * RR + r) * DIM * DIM;
    for (int i = tx; i < 2048; i += 256) {
        uint4 w = *(const uint4*)(Bsrc + i * 8);
        int o = i >> 4, d = (i & 15) * 8;
        *(uint4*)&b_lds[o][d] = w;
    }
    for (int i = tx; i < 1024; i += 256) {
        int row = i >> 4, seg = (i & 15) * 8;
        int n = n0 + row;
        uint4 w = make_uint4(0u, 0u, 0u, 0u);
        if (n < N_NODES) w = *(const uint4*)(h + (long)n * DIM + seg);
        *(uint4*)&a_lds[row][seg] = w;
    }
    __syncthreads();
    int wv = tx >> 6, lane = tx & 63;
    int m16 = lane & 15, quad = lane >> 4;
    f32x4 acc[8];
#pragma unroll
    for (int c = 0; c < 8; c++) acc[c] = (f32x4){0.f, 0.f, 0.f, 0.f};
    for (int ks = 0; ks < 4; ks++) {
        int koff = ks * 32 + quad * 8;
        bf16x8 af = *(const bf16x8*)(const void*)&a_lds[wv * 16 + m16][koff];
#pragma unroll
        for (int c = 0; c < 8; c++) {
            bf16x8 bfr = *(const bf16x8*)(const void*)&b_lds[c * 16 + m16][koff];
            acc[c] = __builtin_amdgcn_mfma_f32_16x16x32_bf16(af, bfr, acc[c], 0, 0, 0);
        }
    }
    __syncthreads();
#pragma unroll
    for (int c = 0; c < 8; c++) {
#pragma unroll
        for (int i = 0; i < 4; i++) {
            int row = wv * 16 + quad * 4 + i;
            int col = c * 16 + m16;
            a_lds[row][col] = f_to_bf16(acc[c][i]);
        }
    }
    __syncthreads();
    for (int i = tx; i < 1024; i += 256) {
        int row = i >> 4, seg = (i & 15) * 8;
        int n = n0 + row;
        if (n < N_NODES)
            *(uint4*)(P + (long)n * (RR * DIM) + r * DIM + seg) = *(const uint4*)&a_lds[row][seg];
    }
}

// ---------- gather: 4 edge groups/wave, unrolled 2 ----------
__global__ void cg_gather4(const unsigned short* __restrict__ P, const int* __restrict__ rowptr,
                           const int* __restrict__ eidx, const float* __restrict__ cv,
                           unsigned short* __restrict__ hout) {
    int wid  = (blockIdx.x * 256 + threadIdx.x) >> 6;
    int lane = threadIdx.x & 63;
    if (wid >= N_NODES) return;
    int eg = lane >> 4;
    int ol = lane & 15;
    int start = rowptr[wid];
    int end   = (wid + 1 < N_NODES) ? rowptr[wid + 1] : N_EDGES;
    float a[8] = {0.f, 0.f, 0.f, 0.f, 0.f, 0.f, 0.f, 0.f};
    int j = start + eg;
    for (; j + 4 < end; j += 8) {
        int v0 = eidx[j];
        int v1 = eidx[j + 4];
        const uint4 w0 = *(const uint4*)(P + (long)(v0 >> 2) * (RR * DIM) + (v0 & 3) * DIM + ol * 8);
        const uint4 w1 = *(const uint4*)(P + (long)(v1 >> 2) * (RR * DIM) + (v1 & 3) * DIM + ol * 8);
        a[0] += bf16_to_f((unsigned short)(w0.x & 0xFFFFu)) + bf16_to_f((unsigned short)(w1.x & 0xFFFFu));
        a[1] += bf16_to_f((unsigned short)(w0.x >> 16))     + bf16_to_f((unsigned short)(w1.x >> 16));
        a[2] += bf16_to_f((unsigned short)(w0.y & 0xFFFFu)) + bf16_to_f((unsigned short)(w1.y & 0xFFFFu));
        a[3] += bf16_to_f((unsigned short)(w0.y >> 16))     + bf16_to_f((unsigned short)(w1.y >> 16));
        a[4] += bf16_to_f((unsigned short)(w0.z & 0xFFFFu)) + bf16_to_f((unsigned short)(w1.z & 0xFFFFu));
        a[5] += bf16_to_f((unsigned short)(w0.z >> 16))     + bf16_to_f((unsigned short)(w1.z >> 16));
        a[6] += bf16_to_f((unsigned short)(w0.w & 0xFFFFu)) + bf16_to_f((unsigned short)(w1.w & 0xFFFFu));
        a[7] += bf16_to_f((unsigned short)(w0.w >> 16))     + bf16_to_f((unsigned short)(w1.w >> 16));
    }
    if (j < end) {
        int v = eidx[j];
        const uint4 w = *(const uint4*)(P + (long)(v >> 2) * (RR * DIM) + (v & 3) * DIM + ol * 8);
        a[0] += bf16_to_f((unsigned short)(w.x & 0xFFFFu));
        a[1] += bf16_to_f((unsigned short)(w.x >> 16));
        a[2] += bf16_to_f((unsigned short)(w.y & 0xFFFFu));
        a[3] += bf16_to_f((unsigned short)(w.y >> 16));
        a[4] += bf16_to_f((unsigned short)(w.z & 0xFFFFu));
        a[5] += bf16_to_f((unsigned short)(w.z >> 16));
        a[6] += bf16_to_f((unsigned short)(w.w & 0xFFFFu));
        a[7] += bf16_to_f((unsigned short)(w.w >> 16));
    }
#pragma unroll
    for (int i = 0; i < 8; i++) {
        a[i] += __shfl_xor(a[i], 16);
        a[i] += __shfl_xor(a[i], 32);
    }
    if (eg == 0) {
        int o0 = ol * 8;
        float v[8];
#pragma unroll
        for (int i = 0; i < 8; i++) {
            float s = a[i] + cv[o0 + i];
            v[i] = s > 0.0f ? s : 0.0f;
        }
        uint4 o4;
        o4.x = (unsigned int)f_to_bf16(v[0]) | ((unsigned int)f_to_bf16(v[1]) << 16);
        o4.y = (unsigned int)f_to_bf16(v[2]) | ((unsigned int)f_to_bf16(v[3]) << 16);
        o4.z = (unsigned int)f_to_bf16(v[4]) | ((unsigned int)f_to_bf16(v[5]) << 16);
        o4.w = (unsigned int)f_to_bf16(v[6]) | ((unsigned int)f_to_bf16(v[7]) << 16);
        *(uint4*)(hout + (long)wid * DIM + o0) = o4;
    }
}

// ---------- fused mean-pool + logits: one block per graph ----------
__global__ void cg_pool_logits(const unsigned short* __restrict__ h, const int* __restrict__ batch,
                               const void* __restrict__ cls_W, const void* __restrict__ cls_b,
                               const int* __restrict__ flagp, void* __restrict__ out) {
    __shared__ float acc_s[4][DIM];
    __shared__ float emb_s[DIM];
    int g   = blockIdx.x;
    int tid = threadIdx.x;
    int wv  = tid >> 6;
    int lane = tid & 63;
    int sub = lane >> 4;
    int ol  = lane & 15;
    int isbf = *flagp;
    int lo = 0, hi = N_NODES;
    while (lo < hi) { int mid = (lo + hi) >> 1; if (batch[mid] < g) lo = mid + 1; else hi = mid; }
    int start = lo;
    hi = N_NODES;
    while (lo < hi) { int mid = (lo + hi) >> 1; if (batch[mid] < g + 1) lo = mid + 1; else hi = mid; }
    int end = lo;
    float a[8] = {0.f, 0.f, 0.f, 0.f, 0.f, 0.f, 0.f, 0.f};
    for (int n = start + wv * 4 + sub; n < end; n += 16) {
        uint4 w = *(const uint4*)(h + (long)n * DIM + ol * 8);
        a[0] += bf16_to_f((unsigned short)(w.x & 0xFFFFu));
        a[1] += bf16_to_f((unsigned short)(w.x >> 16));
        a[2] += bf16_to_f((unsigned short)(w.y & 0xFFFFu));
        a[3] += bf16_to_f((unsigned short)(w.y >> 16));
        a[4] += bf16_to_f((unsigned short)(w.z & 0xFFFFu));
        a[5] += bf16_to_f((unsigned short)(w.z >> 16));
        a[6] += bf16_to_f((unsigned short)(w.w & 0xFFFFu));
        a[7] += bf16_to_f((unsigned short)(w.w >> 16));
    }
#pragma unroll
    for (int i = 0; i < 8; i++) {
        a[i] += __shfl_xor(a[i], 16);
        a[i] += __shfl_xor(a[i], 32);
    }
    if (sub == 0) {
#pragma unroll
        for (int i = 0; i < 8; i++) acc_s[wv][ol * 8 + i] = a[i];
    }
    __syncthreads();
    int cnt = end - start;
    float inv = 1.0f / (float)(cnt > 1 ? cnt : 1);
    if (tid < DIM) {
        float e = (acc_s[0][tid] + acc_s[1][tid] + acc_s[2][tid] + acc_s[3][tid]) * inv;
        emb_s[tid] = e;
        storef(out, (long)g * DIM + tid, e, isbf);
    }
    __syncthreads();
    if (tid < 128) {
        int c  = tid >> 4;
        int kk = tid & 15;
        float p = 0.0f;
#pragma unroll
        for (int k = kk * 8; k < kk * 8 + 8; k++)
            p += emb_s[k] * loadf(cls_W, (long)k * CC + c, isbf);
        p += __shfl_xor(p, 1);
        p += __shfl_xor(p, 2);
        p += __shfl_xor(p, 4);
        p += __shfl_xor(p, 8);
        if (kk == 0)
            storef(out, (long)GG * DIM + g * CC + c, p + loadf(cls_b, c, isbf), isbf);
    }
}

extern "C" void kernel_launch(void* const* d_in, const int* in_sizes, int n_in,
                              void* d_out, int out_size, void* d_ws, size_t ws_size,
                              hipStream_t stream) {
    const void* x      = d_in[0];
    const void* W_het  = d_in[1];
    const void* b_het  = d_in[2];
    const void* conv_W = d_in[3];
    const void* conv_b = d_in[4];
    const void* fuse_W = d_in[5];
    const void* fuse_b = d_in[6];
    const void* cls_W  = d_in[7];
    const void* cls_b  = d_in[8];
    const int* node_type  = (const int*)d_in[9];
    const int* edge_index = (const int*)d_in[10];
    const int* edge_type  = (const int*)d_in[11];
    const int* batch      = (const int*)d_in[12];

    // workspace layout (bytes, 16B aligned)
    char* base = (char*)d_ws;
    unsigned short* hbf      = (unsigned short*)(base + 0);          // 12,800,000
    unsigned short* P        = (unsigned short*)(base + 12800000);   // 51,200,000
    unsigned short* xb       = (unsigned short*)(base + 64000000);   // 12,800,000
    unsigned short* Wt       = (unsigned short*)(base + 76800000);   //    131,072
    float*          bhf      = (float*)(base + 76931072);            //      2,048
    unsigned short* M2t      = (unsigned short*)(base + 76933120);   //    262,144
    float*          cvec     = (float*)(base + 77195264);            //      1,024
    int*            rowptr   = (int*)(base + 77196288);              //    200,032
    int*            chist    = (int*)(base + 77396320);              //  chist[196]+tb[16]
    int*            tb       = chist + NCB;
    int*            blockoff = (int*)(base + 77397408);              //      1,024
    int*            ccursor  = (int*)(base + 77398432);              //      1,024
    int*            eidx     = (int*)(base + 77399456);              //  2,400,000
    int*            tlist    = (int*)(base + 79799456);              //    200,000
    int*            flag     = (int*)(base + 79999456);              //          4
    int2*           tmp2     = (int2*)(base + 79999472);             //  4,800,000 (total ~84.8 MB)

    cg_init<<<1, 256, 0, stream>>>((const unsigned int*)x, flag, chist);
    cg_hist_canon<<<FB + CB, 256, 0, stream>>>(edge_index, node_type, chist, tb,
                                               x, W_het, b_het, conv_W, fuse_W,
                                               conv_b, fuse_b, flag,
                                               xb, Wt, bhf, M2t, cvec);
    cg_scan196<<<1, 256, 0, stream>>>(chist, blockoff, ccursor, tb);
    cg_tfill<<<TB, 256, 0, stream>>>(node_type, tb, tlist);
    // sortA (coarse bin) runs alongside hetero MFMA
    cg_sortA_hetero<<<FB + 4 * NBH, 256, 0, stream>>>(edge_index, edge_type, ccursor, tmp2,
                                                      xb, Wt, bhf, tlist, tb, hbf);
    // sortB (local count+scan -> rowptr, line-local eidx writes) alongside pgemm l=0
    cg_sortB_pgemm<<<NCB + 4 * NBH, 256, 0, stream>>>(tmp2, blockoff, rowptr, eidx,
                                                      hbf, M2t, P);
    cg_gather4<<<(N_NODES * 64 + 255) / 256, 256, 0, stream>>>(
        P, rowptr, eidx, cvec, hbf);
    cg_pgemm_mfma<<<dim3(NBH, RR), 256, 0, stream>>>(hbf, M2t, 1, P);
    cg_gather4<<<(N_NODES * 64 + 255) / 256, 256, 0, stream>>>(
        P, rowptr, eidx, cvec + DIM, hbf);

    cg_pool_logits<<<GG, 256, 0, stream>>>(hbf, batch, cls_W, cls_b, flag, d_out);
}